// Round 13
// baseline (444.661 us; speedup 1.0000x reference)
//
#include <hip/hip_runtime.h>

#define I_F 8192
#define O_F 8192
#define NSPLIT 64
#define CHUNK (I_F / NSPLIT)   // 128 i-rows per block
#define QB 8                   // qidx loads in flight per thread

// 3-level cndmask tree: select lut[q] from 8 values held in 2 float4 regs.
__device__ __forceinline__ float lut_sel(const float4& lo, const float4& hi, int q) {
    const bool b2 = (q & 4) != 0;
    const float s0 = b2 ? hi.x : lo.x;
    const float s1 = b2 ? hi.y : lo.y;
    const float s2 = b2 ? hi.z : lo.z;
    const float s3 = b2 ? hi.w : lo.w;
    const bool b1 = (q & 2) != 0;
    const float t0 = b1 ? s2 : s0;
    const float t1 = b1 ? s3 : s1;
    return (q & 1) ? t1 : t0;
}

// Build xT[i][b] = x[b][i] (32B contiguous per i). grid = 32 x 256.
__global__ __launch_bounds__(256) void prolog_kernel(const float* __restrict__ x,
                                                     float* __restrict__ xT) {
    const int t = blockIdx.x * 256 + threadIdx.x;   // 0..8191
    float4 lo, hi;
    lo.x = x[0 * I_F + t];
    lo.y = x[1 * I_F + t];
    lo.z = x[2 * I_F + t];
    lo.w = x[3 * I_F + t];
    hi.x = x[4 * I_F + t];
    hi.y = x[5 * I_F + t];
    hi.z = x[6 * I_F + t];
    hi.w = x[7 * I_F + t];
    ((float4*)xT)[t * 2]     = lo;
    ((float4*)xT)[t * 2 + 1] = hi;
}

// Dense partial, LOW-REGISTER-PRESSURE variant (spill hypothesis test).
// 2 cols/thread, 512-thread blocks: live state = acc[2][8](16) + lA/lB(16)
// + qb[8] int2 (16) + misc ~= 70 VGPR -> spill-free under ANY compiler
// occupancy choice (R1's measured VGPR_Count=64 showed the 4-col variants
// were under-allocated and spilling scratch every inner iteration).
// grid = (8, NSPLIT) of 512 thr; block covers 1024 cols x CHUNK rows.
__global__ __launch_bounds__(512, 2) void dense_kernel(const int* __restrict__ qidx,
                                                       const float* __restrict__ lut,
                                                       const float* __restrict__ xT,
                                                       float* __restrict__ P) {
    __shared__ float4 xs[CHUNK][2];    // xs[r] = {x[0..3][i0+r], x[4..7][i0+r]}

    const int tid = threadIdx.x;
    const int col0 = blockIdx.x * 1024 + tid * 2;
    const int i0 = blockIdx.y * CHUNK;

    // Stage x-chunk: CHUNK*2 = 256 float4s, coalesced.
    if (tid < CHUNK * 2)
        ((float4*)xs)[tid] = ((const float4*)(xT + (size_t)i0 * 8))[tid];

    // 2 columns' LUT rows: 8 f32 each -> 2 float4 regs/col.
    float4 lA[2], lB[2];
#pragma unroll
    for (int c = 0; c < 2; ++c) {
        const float4* p = (const float4*)(lut + (size_t)(col0 + c) * 8);
        lA[c] = p[0];
        lB[c] = p[1];
    }

    float acc[2][8];
#pragma unroll
    for (int c = 0; c < 2; ++c)
#pragma unroll
        for (int b = 0; b < 8; ++b) acc[c][b] = 0.0f;

    __syncthreads();

    const int2* qp = (const int2*)qidx + (size_t)i0 * (O_F / 2) + (col0 >> 1);

    for (int t = 0; t < CHUNK; t += QB) {
        int2 qb[QB];
#pragma unroll
        for (int k = 0; k < QB; ++k)
            qb[k] = qp[(size_t)(t + k) * (O_F / 2)];

#pragma unroll
        for (int k = 0; k < QB; ++k) {
            const float4 xlo = xs[t + k][0];   // LDS broadcast
            const float4 xhi = xs[t + k][1];
#pragma unroll
            for (int c = 0; c < 2; ++c) {
                const int q = (c == 0) ? qb[k].x : qb[k].y;
                const float w = lut_sel(lA[c], lB[c], q);
                acc[c][0] += xlo.x * w;
                acc[c][1] += xlo.y * w;
                acc[c][2] += xlo.z * w;
                acc[c][3] += xlo.w * w;
                acc[c][4] += xhi.x * w;
                acc[c][5] += xhi.y * w;
                acc[c][6] += xhi.z * w;
                acc[c][7] += xhi.w * w;
            }
        }
    }

    // P layout: [split][b][O_F]; per b one float2 covering the 2 owned cols
    // (wave writes 1 KB contiguous per b).
    float* Pb = P + ((size_t)blockIdx.y * 8) * O_F + col0;
#pragma unroll
    for (int b = 0; b < 8; ++b)
        *(float2*)(Pb + (size_t)b * O_F) = make_float2(acc[0][b], acc[1][b]);
}

// Sparse: one wave per output row o; 128 nnz -> 2 per lane; gather from
// L2-resident xT; butterfly-reduce; lane 0 stores 8 values to sp. NO atomics.
__global__ __launch_bounds__(256) void sparse_kernel(const int* __restrict__ rows,
                                                     const int* __restrict__ cols,
                                                     const float* __restrict__ vals,
                                                     const float* __restrict__ xT,
                                                     float* __restrict__ sp) {
    const int wave = threadIdx.x >> 6;
    const int lane = threadIdx.x & 63;
    const int o = blockIdx.x * 4 + wave;
    const int r0 = rows[o];
    const int r1 = rows[o + 1];

    float acc[8];
#pragma unroll
    for (int b = 0; b < 8; ++b) acc[b] = 0.0f;

    for (int k = r0 + lane; k < r1; k += 64) {
        const int   col = cols[k];
        const float v   = vals[k];
        const float4* xp = (const float4*)(xT + (size_t)col * 8);
        const float4 xlo = xp[0];
        const float4 xhi = xp[1];
        acc[0] += v * xlo.x;
        acc[1] += v * xlo.y;
        acc[2] += v * xlo.z;
        acc[3] += v * xlo.w;
        acc[4] += v * xhi.x;
        acc[5] += v * xhi.y;
        acc[6] += v * xhi.z;
        acc[7] += v * xhi.w;
    }

#pragma unroll
    for (int s = 1; s < 64; s <<= 1)
#pragma unroll
        for (int b = 0; b < 8; ++b) acc[b] += __shfl_xor(acc[b], s, 64);

    if (lane == 0) {
#pragma unroll
        for (int b = 0; b < 8; ++b) sp[(size_t)b * O_F + o] = acc[b];
    }
}

// out[t] = sp[t] + sum_s P[s][t]  (t over 8*O_F elems, float4-vectorized).
// grid = 128 x 128.
__global__ __launch_bounds__(128) void reduce_kernel(const float* __restrict__ P,
                                                     const float* __restrict__ sp,
                                                     float* __restrict__ out) {
    const int t4 = blockIdx.x * 128 + threadIdx.x;   // 0..16383 (float4 units)
    float4 s = ((const float4*)sp)[t4];
#pragma unroll 8
    for (int k = 0; k < NSPLIT; ++k) {
        const float4 p = ((const float4*)P)[(size_t)k * (8 * O_F / 4) + t4];
        s.x += p.x; s.y += p.y; s.z += p.z; s.w += p.w;
    }
    ((float4*)out)[t4] = s;
}

extern "C" void kernel_launch(void* const* d_in, const int* in_sizes, int n_in,
                              void* d_out, int out_size, void* d_ws, size_t ws_size,
                              hipStream_t stream) {
    const float* x    = (const float*)d_in[0];
    const int*   qidx = (const int*)d_in[1];
    const float* lut  = (const float*)d_in[2];
    const int*   rows = (const int*)d_in[3];
    const int*   cols = (const int*)d_in[4];
    const float* vals = (const float*)d_in[5];
    float* out = (float*)d_out;

    // Workspace: xT (256KB) | sp (256KB) | P (NSPLIT * 256KB = 16MB)
    float* xT = (float*)d_ws;
    float* sp = xT + (size_t)I_F * 8;
    float* P  = sp + (size_t)O_F * 8;

    prolog_kernel<<<I_F / 256, 256, 0, stream>>>(x, xT);
    // Dense launched TWICE (idempotent writes): total-time delta pins the
    // per-dispatch dense cost exactly: D = (dur - 392.5 + 120) / 2.
    dense_kernel<<<dim3(8, NSPLIT), 512, 0, stream>>>(qidx, lut, xT, P);
    dense_kernel<<<dim3(8, NSPLIT), 512, 0, stream>>>(qidx, lut, xT, P);
    sparse_kernel<<<O_F / 4, 256, 0, stream>>>(rows, cols, vals, xT, sp);
    reduce_kernel<<<(8 * O_F / 4) / 128, 128, 0, stream>>>(P, sp, out);
}

// Round 14
// 416.967 us; speedup vs baseline: 1.0664x; 1.0664x over previous
//
#include <hip/hip_runtime.h>
#include <hip/hip_fp16.h>

#define I_F 8192
#define O_F 8192
#define NSPLIT 256
#define RPB 32                 // rows per block (I_F / NSPLIT)

// Prolog: build xT[i][b] = x[b][i] AND pack lut to f16 (8 halfs = uint4 per
// col). grid = 32 x 256 (t = 0..8191 covers both tables).
__global__ __launch_bounds__(256) void prolog_kernel(const float* __restrict__ x,
                                                     const float* __restrict__ lut,
                                                     float* __restrict__ xT,
                                                     uint4* __restrict__ lutH) {
    const int t = blockIdx.x * 256 + threadIdx.x;   // 0..8191
    float4 lo, hi;
    lo.x = x[0 * I_F + t];
    lo.y = x[1 * I_F + t];
    lo.z = x[2 * I_F + t];
    lo.w = x[3 * I_F + t];
    hi.x = x[4 * I_F + t];
    hi.y = x[5 * I_F + t];
    hi.z = x[6 * I_F + t];
    hi.w = x[7 * I_F + t];
    ((float4*)xT)[t * 2]     = lo;
    ((float4*)xT)[t * 2 + 1] = hi;

    const float4* lp = (const float4*)(lut + (size_t)t * 8);
    const float4 l0 = lp[0];
    const float4 l1 = lp[1];
    uint4 h;
    h.x = (unsigned)__half_as_ushort(__float2half_rn(l0.x)) |
          ((unsigned)__half_as_ushort(__float2half_rn(l0.y)) << 16);
    h.y = (unsigned)__half_as_ushort(__float2half_rn(l0.z)) |
          ((unsigned)__half_as_ushort(__float2half_rn(l0.w)) << 16);
    h.z = (unsigned)__half_as_ushort(__float2half_rn(l1.x)) |
          ((unsigned)__half_as_ushort(__float2half_rn(l1.y)) << 16);
    h.w = (unsigned)__half_as_ushort(__float2half_rn(l1.z)) |
          ((unsigned)__half_as_ushort(__float2half_rn(l1.w)) << 16);
    lutH[t] = h;
}

// Dense partial with FULLY LINEAR qidx walk: 1024-thread block covers the
// entire 8192-col row (thread owns 8 consecutive cols), so per row-step the
// block reads one contiguous 32 KB row and its whole slab (32 rows = 1 MB)
// is linear — the access shape measured at 6.6 TB/s (R11 probe, same
// 16 waves/CU). Register budget: f16 LUT 32 + acc 64 + ~26 misc ~= 122 < 128
// (launch_bounds(1024,4) -> exactly 16 waves/CU). grid = NSPLIT blocks.
__global__ __launch_bounds__(1024, 4) void dense_kernel(const int* __restrict__ qidx,
                                                        const uint4* __restrict__ lutH,
                                                        const float* __restrict__ xT,
                                                        float* __restrict__ P) {
    __shared__ float4 xs[RPB][2];      // xs[r] = {x[0..3][i0+r], x[4..7][i0+r]}

    const int tid = threadIdx.x;
    const int split = blockIdx.x;
    const int i0 = split * RPB;
    const int col0 = tid * 8;

    if (tid < RPB * 2)
        ((float4*)xs)[tid] = ((const float4*)(xT + (size_t)i0 * 8))[tid];

    // 8 cols' LUTs as packed f16: 8 x uint4 = 32 VGPR.
    uint4 lh[8];
#pragma unroll
    for (int c = 0; c < 8; ++c) lh[c] = lutH[col0 + c];

    float acc[8][8];
#pragma unroll
    for (int c = 0; c < 8; ++c)
#pragma unroll
        for (int b = 0; b < 8; ++b) acc[c][b] = 0.0f;

    __syncthreads();

    const int4* qp = (const int4*)(qidx + (size_t)i0 * O_F) + tid * 2;

    for (int r = 0; r < RPB; ++r) {
        const int4 qa = qp[(size_t)r * (O_F / 4)];        // cols col0+0..3
        const int4 qb = qp[(size_t)r * (O_F / 4) + 1];    // cols col0+4..7
        const float4 xlo = xs[r][0];   // LDS broadcast
        const float4 xhi = xs[r][1];
#pragma unroll
        for (int c = 0; c < 8; ++c) {
            const int q = (c < 4) ? ((c == 0) ? qa.x : (c == 1) ? qa.y : (c == 2) ? qa.z : qa.w)
                                  : ((c == 4) ? qb.x : (c == 5) ? qb.y : (c == 6) ? qb.z : qb.w);
            const unsigned a = (q & 4) ? ((q & 2) ? lh[c].w : lh[c].z)
                                       : ((q & 2) ? lh[c].y : lh[c].x);
            const unsigned sel = (q & 1) ? (a >> 16) : (a & 0xffffu);
            const float w = __half2float(__ushort_as_half((unsigned short)sel));
            acc[c][0] += xlo.x * w;
            acc[c][1] += xlo.y * w;
            acc[c][2] += xlo.z * w;
            acc[c][3] += xlo.w * w;
            acc[c][4] += xhi.x * w;
            acc[c][5] += xhi.y * w;
            acc[c][6] += xhi.z * w;
            acc[c][7] += xhi.w * w;
        }
    }

    // P layout: [split][b][O_F]; per b two float4 covering the 8 owned cols.
    float* Pb = P + ((size_t)split * 8) * O_F + col0;
#pragma unroll
    for (int b = 0; b < 8; ++b) {
        *(float4*)(Pb + (size_t)b * O_F)     = make_float4(acc[0][b], acc[1][b], acc[2][b], acc[3][b]);
        *(float4*)(Pb + (size_t)b * O_F + 4) = make_float4(acc[4][b], acc[5][b], acc[6][b], acc[7][b]);
    }
}

// Sparse: one wave per output row o; 128 nnz -> 2 per lane; gather from
// L2-resident xT; butterfly-reduce; lane 0 stores 8 values to sp. NO atomics.
__global__ __launch_bounds__(256) void sparse_kernel(const int* __restrict__ rows,
                                                     const int* __restrict__ cols,
                                                     const float* __restrict__ vals,
                                                     const float* __restrict__ xT,
                                                     float* __restrict__ sp) {
    const int wave = threadIdx.x >> 6;
    const int lane = threadIdx.x & 63;
    const int o = blockIdx.x * 4 + wave;
    const int r0 = rows[o];
    const int r1 = rows[o + 1];

    float acc[8];
#pragma unroll
    for (int b = 0; b < 8; ++b) acc[b] = 0.0f;

    for (int k = r0 + lane; k < r1; k += 64) {
        const int   col = cols[k];
        const float v   = vals[k];
        const float4* xp = (const float4*)(xT + (size_t)col * 8);
        const float4 xlo = xp[0];
        const float4 xhi = xp[1];
        acc[0] += v * xlo.x;
        acc[1] += v * xlo.y;
        acc[2] += v * xlo.z;
        acc[3] += v * xlo.w;
        acc[4] += v * xhi.x;
        acc[5] += v * xhi.y;
        acc[6] += v * xhi.z;
        acc[7] += v * xhi.w;
    }

#pragma unroll
    for (int s = 1; s < 64; s <<= 1)
#pragma unroll
        for (int b = 0; b < 8; ++b) acc[b] += __shfl_xor(acc[b], s, 64);

    if (lane == 0) {
#pragma unroll
        for (int b = 0; b < 8; ++b) sp[(size_t)b * O_F + o] = acc[b];
    }
}

// out[t] = sp[t] + sum_s P[s][t]  (t over 8*O_F elems, float4-vectorized).
// grid = 128 x 128; per k-step the grid reads one contiguous 256 KB split.
__global__ __launch_bounds__(128) void reduce_kernel(const float* __restrict__ P,
                                                     const float* __restrict__ sp,
                                                     float* __restrict__ out) {
    const int t4 = blockIdx.x * 128 + threadIdx.x;   // 0..16383 (float4 units)
    float4 s = ((const float4*)sp)[t4];
#pragma unroll 8
    for (int k = 0; k < NSPLIT; ++k) {
        const float4 p = ((const float4*)P)[(size_t)k * (8 * O_F / 4) + t4];
        s.x += p.x; s.y += p.y; s.z += p.z; s.w += p.w;
    }
    ((float4*)out)[t4] = s;
}

extern "C" void kernel_launch(void* const* d_in, const int* in_sizes, int n_in,
                              void* d_out, int out_size, void* d_ws, size_t ws_size,
                              hipStream_t stream) {
    const float* x    = (const float*)d_in[0];
    const int*   qidx = (const int*)d_in[1];
    const float* lut  = (const float*)d_in[2];
    const int*   rows = (const int*)d_in[3];
    const int*   cols = (const int*)d_in[4];
    const float* vals = (const float*)d_in[5];
    float* out = (float*)d_out;

    // Workspace: xT (256KB) | sp (256KB) | lutH (128KB) | P (64MB)
    float* xT   = (float*)d_ws;
    float* sp   = xT + (size_t)I_F * 8;
    uint4* lutH = (uint4*)(sp + (size_t)O_F * 8);
    float* P    = (float*)(lutH + O_F);

    prolog_kernel<<<I_F / 256, 256, 0, stream>>>(x, lut, xT, lutH);
    dense_kernel<<<NSPLIT, 1024, 0, stream>>>(qidx, lutH, xT, P);
    sparse_kernel<<<O_F / 4, 256, 0, stream>>>(rows, cols, vals, xT, sp);
    reduce_kernel<<<(8 * O_F / 4) / 128, 128, 0, stream>>>(P, sp, out);
}